// Round 1
// baseline (1059.092 us; speedup 1.0000x reference)
//
#include <hip/hip_runtime.h>
#include <hip/hip_bf16.h>

#define B_   2
#define S_   1024
#define H_   2048
#define NH_  32
#define NKV_ 8
#define HD_  64
#define T_   (B_*S_)          // 2048 tokens
#define GROUPS_ (NH_/NKV_)    // 4

// ------------------------------------------------------------------
// fp32 tiled GEMM: C[M,N] = A[M,K] @ W[K,N], all row-major.
// BM=BN=64, BK=32, 256 threads, 4x4 micro-tile per thread.
// ------------------------------------------------------------------
__global__ __launch_bounds__(256) void gemm_f32(
    const float* __restrict__ A, const float* __restrict__ Bm,
    float* __restrict__ C, int M, int N, int K)
{
    const int BM = 64, BN = 64, BK = 32;
    __shared__ float As[64][32 + 4];   // +4 pad: keeps 16B align, breaks bank stride
    __shared__ float Bs[32][64 + 4];

    const int bm = blockIdx.y * BM;
    const int bn = blockIdx.x * BN;
    const int tid = threadIdx.x;
    const int tx = tid & 15;    // output col group (tx*4 .. +4)
    const int ty = tid >> 4;    // output row group (ty*4 .. +4)

    float acc[4][4] = {};

    for (int k0 = 0; k0 < K; k0 += BK) {
        // A tile: 64x32 = 512 float4, 2 per thread
        #pragma unroll
        for (int i = 0; i < 2; ++i) {
            int t  = tid * 2 + i;          // 0..511
            int r  = t >> 3;               // 8 float4 per row
            int c4 = t & 7;
            float4 v = *reinterpret_cast<const float4*>(
                &A[(size_t)(bm + r) * K + k0 + c4 * 4]);
            *reinterpret_cast<float4*>(&As[r][c4 * 4]) = v;
        }
        // B tile: 32x64 = 512 float4, 2 per thread
        #pragma unroll
        for (int i = 0; i < 2; ++i) {
            int t  = tid * 2 + i;
            int r  = t >> 4;               // 16 float4 per row
            int c4 = t & 15;
            float4 v = *reinterpret_cast<const float4*>(
                &Bm[(size_t)(k0 + r) * N + bn + c4 * 4]);
            *reinterpret_cast<float4*>(&Bs[r][c4 * 4]) = v;
        }
        __syncthreads();

        #pragma unroll
        for (int kk = 0; kk < BK; ++kk) {
            float a[4], b[4];
            #pragma unroll
            for (int i = 0; i < 4; ++i) a[i] = As[ty * 4 + i][kk];
            #pragma unroll
            for (int j = 0; j < 4; ++j) b[j] = Bs[kk][tx * 4 + j];
            #pragma unroll
            for (int i = 0; i < 4; ++i)
                #pragma unroll
                for (int j = 0; j < 4; ++j)
                    acc[i][j] = fmaf(a[i], b[j], acc[i][j]);
        }
        __syncthreads();
    }

    #pragma unroll
    for (int i = 0; i < 4; ++i) {
        float4 v = make_float4(acc[i][0], acc[i][1], acc[i][2], acc[i][3]);
        *reinterpret_cast<float4*>(&C[(size_t)(bm + ty * 4 + i) * N + bn + tx * 4]) = v;
    }
}

// ------------------------------------------------------------------
// Fused RMSNorm (over full row of DIM channels) + RoPE (per 64-d head).
// One block (256 thr) per token; in-place on x[T, DIM].
// cos/sin: [B,S,64] indexed by token*64 + (d&63).
// ------------------------------------------------------------------
template<int DIM>
__global__ __launch_bounds__(256) void rmsnorm_rope(
    float* __restrict__ x, const float* __restrict__ w,
    const float* __restrict__ cosb, const float* __restrict__ sinb)
{
    __shared__ float row[DIM];
    __shared__ float red[4];
    const int t   = blockIdx.x;
    const int tid = threadIdx.x;

    float ss = 0.f;
    for (int i = tid; i < DIM / 4; i += 256) {
        float4 v = *reinterpret_cast<const float4*>(&x[(size_t)t * DIM + i * 4]);
        *reinterpret_cast<float4*>(&row[i * 4]) = v;
        ss += v.x * v.x + v.y * v.y + v.z * v.z + v.w * v.w;
    }
    #pragma unroll
    for (int off = 1; off < 64; off <<= 1) ss += __shfl_xor(ss, off);
    if ((tid & 63) == 0) red[tid >> 6] = ss;
    __syncthreads();
    const float var  = (red[0] + red[1] + red[2] + red[3]) * (1.0f / DIM);
    const float rstd = rsqrtf(var + 1e-6f);

    for (int i = tid; i < DIM; i += 256) {
        const int dh = i & 63, base = i & ~63;
        const float y = row[i] * rstd * w[i];
        const float other = (dh < 32)
            ? -(row[base + dh + 32] * rstd * w[base + dh + 32])
            :  (row[base + dh - 32] * rstd * w[base + dh - 32]);
        const float c  = cosb[(size_t)t * 64 + dh];
        const float sn = sinb[(size_t)t * 64 + dh];
        x[(size_t)t * DIM + i] = y * c + other * sn;
    }
}

// ------------------------------------------------------------------
// fp32 flash-style causal GQA attention.
// grid: (B*NH, S/64). Block 256 thr: 4 lanes per query row.
// q: [T, NH*64] (normed+roped), k/v: [T, NKV*64], out: [T, NH*64]
// ------------------------------------------------------------------
__global__ __launch_bounds__(256) void attn_f32(
    const float* __restrict__ qb, const float* __restrict__ kb,
    const float* __restrict__ vb, float* __restrict__ ob)
{
    __shared__ float Qs[64][HD_ + 4];
    __shared__ float Ks[64][HD_ + 4];
    __shared__ float Vs[64][HD_ + 4];
    __shared__ float Ps[64][64 + 4];

    const int head = blockIdx.x;        // b*NH + h
    const int qt   = blockIdx.y;        // query tile
    const int b    = head / NH_;
    const int h    = head % NH_;
    const int kvh  = h / GROUPS_;
    const int tid  = threadIdx.x;
    const int r    = tid >> 2;          // query row in tile
    const int part = tid & 3;           // 16-wide column/dim chunk

    // load Q tile (64 rows x 64 d): 1024 float4, 4 per thread
    #pragma unroll
    for (int i = 0; i < 4; ++i) {
        int t = tid * 4 + i;
        int rr = t >> 4, c4 = t & 15;
        float4 v = *reinterpret_cast<const float4*>(
            &qb[((size_t)(b * S_ + qt * 64 + rr)) * (NH_ * 64) + h * 64 + c4 * 4]);
        *reinterpret_cast<float4*>(&Qs[rr][c4 * 4]) = v;
    }

    float m = -1e30f, l = 0.f;
    float o[16] = {};
    const int qs_glob = qt * 64 + r;

    for (int kt = 0; kt <= qt; ++kt) {
        __syncthreads();    // prev iter's Ks/Vs/Ps reads done (and Qs ready on iter 0)
        #pragma unroll
        for (int i = 0; i < 4; ++i) {
            int t = tid * 4 + i;
            int rr = t >> 4, c4 = t & 15;
            size_t rowoff = ((size_t)(b * S_ + kt * 64 + rr)) * (NKV_ * 64) + kvh * 64 + c4 * 4;
            *reinterpret_cast<float4*>(&Ks[rr][c4 * 4]) =
                *reinterpret_cast<const float4*>(&kb[rowoff]);
            *reinterpret_cast<float4*>(&Vs[rr][c4 * 4]) =
                *reinterpret_cast<const float4*>(&vb[rowoff]);
        }
        __syncthreads();

        float sc[16];
        float rowmax = -1e30f;
        #pragma unroll
        for (int jj = 0; jj < 16; ++jj) {
            const int j = part * 16 + jj;
            float acc = 0.f;
            #pragma unroll
            for (int d = 0; d < 64; ++d) acc = fmaf(Qs[r][d], Ks[j][d], acc);
            acc *= 0.125f;                       // HD^-0.5
            if (kt * 64 + j > qs_glob) acc = -1e30f;   // causal
            sc[jj] = acc;
            rowmax = fmaxf(rowmax, acc);
        }
        rowmax = fmaxf(rowmax, __shfl_xor(rowmax, 1));
        rowmax = fmaxf(rowmax, __shfl_xor(rowmax, 2));
        const float mnew  = fmaxf(m, rowmax);
        const float alpha = __expf(m - mnew);
        float lsum = 0.f;
        #pragma unroll
        for (int jj = 0; jj < 16; ++jj) {
            const float p = __expf(sc[jj] - mnew);   // masked -> 0
            Ps[r][part * 16 + jj] = p;
            lsum += p;
        }
        lsum += __shfl_xor(lsum, 1);
        lsum += __shfl_xor(lsum, 2);
        l = l * alpha + lsum;
        m = mnew;
        #pragma unroll
        for (int dd = 0; dd < 16; ++dd) o[dd] *= alpha;
        __syncthreads();    // Ps visible to all 4 parts

        for (int j = 0; j < 64; ++j) {
            const float p = Ps[r][j];
            #pragma unroll
            for (int dd = 0; dd < 16; ++dd)
                o[dd] = fmaf(p, Vs[j][part * 16 + dd], o[dd]);
        }
    }

    const float inv_l = 1.f / l;
    #pragma unroll
    for (int dd = 0; dd < 16; ++dd)
        ob[((size_t)(b * S_ + qs_glob)) * (NH_ * 64) + h * 64 + part * 16 + dd]
            = o[dd] * inv_l;
}

// ------------------------------------------------------------------
extern "C" void kernel_launch(void* const* d_in, const int* in_sizes, int n_in,
                              void* d_out, int out_size, void* d_ws, size_t ws_size,
                              hipStream_t stream)
{
    const float* hidden = (const float*)d_in[0];
    const float* cosb   = (const float*)d_in[1];
    const float* sinb   = (const float*)d_in[2];
    // d_in[3] = attention_mask (pure causal; handled analytically)
    const float* wq     = (const float*)d_in[4];
    const float* wk     = (const float*)d_in[5];
    const float* wv     = (const float*)d_in[6];
    const float* wo     = (const float*)d_in[7];
    const float* qnw    = (const float*)d_in[8];
    const float* knw    = (const float*)d_in[9];
    float* out = (float*)d_out;

    float* q_buf    = (float*)d_ws;                       // [2048, 2048] 16 MB
    float* k_buf    = q_buf + (size_t)T_ * 2048;          // [2048, 512]   4 MB
    float* v_buf    = k_buf + (size_t)T_ * 512;           // [2048, 512]   4 MB
    float* attn_buf = v_buf + (size_t)T_ * 512;           // [2048, 2048] 16 MB

    // QKV projections
    gemm_f32<<<dim3(2048 / 64, T_ / 64), 256, 0, stream>>>(hidden, wq, q_buf, T_, 2048, H_);
    gemm_f32<<<dim3(512 / 64,  T_ / 64), 256, 0, stream>>>(hidden, wk, k_buf, T_, 512,  H_);
    gemm_f32<<<dim3(512 / 64,  T_ / 64), 256, 0, stream>>>(hidden, wv, v_buf, T_, 512,  H_);

    // RMSNorm + RoPE (in place)
    rmsnorm_rope<2048><<<T_, 256, 0, stream>>>(q_buf, qnw, cosb, sinb);
    rmsnorm_rope<512 ><<<T_, 256, 0, stream>>>(k_buf, knw, cosb, sinb);

    // causal GQA attention
    attn_f32<<<dim3(B_ * NH_, S_ / 64), 256, 0, stream>>>(q_buf, k_buf, v_buf, attn_buf);

    // output projection
    gemm_f32<<<dim3(2048 / 64, T_ / 64), 256, 0, stream>>>(attn_buf, wo, out, T_, 2048, H_);
}

// Round 2
// 187.860 us; speedup vs baseline: 5.6377x; 5.6377x over previous
//
#include <hip/hip_runtime.h>

#define B_    2
#define S_    1024
#define NH_   32
#define NKV_  8
#define T_    (B_*S_)

typedef unsigned short u16;
typedef __attribute__((ext_vector_type(8))) short bf16x8;
typedef __attribute__((ext_vector_type(4))) float f32x4;

__device__ __forceinline__ float bf2f(u16 u) {
    union { float f; unsigned int i; } c; c.i = ((unsigned int)u) << 16; return c.f;
}
__device__ __forceinline__ u16 f2bf(float f) {
    union { float f; unsigned int u; } c; c.f = f;
    return (u16)((c.u + 0x7FFFu + ((c.u >> 16) & 1u)) >> 16);
}

// async global->LDS, 16B per lane; LDS dest = wave-uniform base + lane*16
__device__ __forceinline__ void gld_lds16(const void* g, void* s) {
    __builtin_amdgcn_global_load_lds(
        (const __attribute__((address_space(1))) void*)g,
        (__attribute__((address_space(3))) void*)s,
        16, 0, 0);
}

// ------------------------------------------------------------------
// elementwise f32 -> bf16
// ------------------------------------------------------------------
__global__ __launch_bounds__(256) void cvt_bf16(
    const float* __restrict__ s, u16* __restrict__ d, int n)
{
    int i = (blockIdx.x * 256 + threadIdx.x) * 8;
    if (i >= n) return;
    float4 v0 = *reinterpret_cast<const float4*>(&s[i]);
    float4 v1 = *reinterpret_cast<const float4*>(&s[i + 4]);
    u16 o[8] = { f2bf(v0.x), f2bf(v0.y), f2bf(v0.z), f2bf(v0.w),
                 f2bf(v1.x), f2bf(v1.y), f2bf(v1.z), f2bf(v1.w) };
    *reinterpret_cast<uint4*>(&d[i]) = *reinterpret_cast<uint4*>(o);
}

// ------------------------------------------------------------------
// pack wq|wk|wv transposed: dst bf16 [3072][2048], dst[n][k] = W[k][n]
// ------------------------------------------------------------------
__global__ __launch_bounds__(256) void pack_wqkvT(
    const float* __restrict__ wq, const float* __restrict__ wk,
    const float* __restrict__ wv, u16* __restrict__ dst)
{
    __shared__ float t[64][65];
    const int n0 = blockIdx.x * 64, k0 = blockIdx.y * 64;
    const int tid = threadIdx.x;
    const float* src; int scol, sN;
    if (n0 < 2048)      { src = wq; scol = n0;        sN = 2048; }
    else if (n0 < 2560) { src = wk; scol = n0 - 2048; sN = 512;  }
    else                { src = wv; scol = n0 - 2560; sN = 512;  }
    #pragma unroll
    for (int i = 0; i < 16; ++i) {
        int e = i * 256 + tid, r = e >> 6, c = e & 63;
        t[r][c] = src[(size_t)(k0 + r) * sN + scol + c];
    }
    __syncthreads();
    #pragma unroll
    for (int i = 0; i < 16; ++i) {
        int e = i * 256 + tid, rr = e >> 6, cc = e & 63;
        dst[(size_t)(n0 + rr) * 2048 + k0 + cc] = f2bf(t[cc][rr]);
    }
}

// ------------------------------------------------------------------
// generic transpose+convert: src f32 [K][N] -> dst bf16 [N][K]
// ------------------------------------------------------------------
__global__ __launch_bounds__(256) void transpose_cvt(
    const float* __restrict__ src, u16* __restrict__ dst, int K, int N)
{
    __shared__ float t[64][65];
    const int n0 = blockIdx.x * 64, k0 = blockIdx.y * 64;
    const int tid = threadIdx.x;
    #pragma unroll
    for (int i = 0; i < 16; ++i) {
        int e = i * 256 + tid, r = e >> 6, c = e & 63;
        t[r][c] = src[(size_t)(k0 + r) * N + n0 + c];
    }
    __syncthreads();
    #pragma unroll
    for (int i = 0; i < 16; ++i) {
        int e = i * 256 + tid, rr = e >> 6, cc = e & 63;
        dst[(size_t)(n0 + rr) * K + k0 + cc] = f2bf(t[cc][rr]);
    }
}

// ------------------------------------------------------------------
// bf16 MFMA GEMM, B^T input.  C[M,N] = A[M,K] @ Bt[N,K]^T
// 128x128 tile, BK=64, 4 waves (2x2), 4x4 16x16 frags per wave.
// ------------------------------------------------------------------
template<bool OUT_BF16>
__global__ __launch_bounds__(256) void gemm_bt(
    const u16* __restrict__ A, const u16* __restrict__ Bt,
    void* __restrict__ Cv, int M, int N, int K)
{
    __shared__ u16 As[128 * 64];
    __shared__ u16 Bs[128 * 64];
    const int bm = blockIdx.y * 128, bn = blockIdx.x * 128;
    const int tid = threadIdx.x;
    const int w = tid >> 6, lane = tid & 63;
    const int wr = w >> 1, wc = w & 1;
    const int l15 = lane & 15, lg = lane >> 4;
    const int srow = lane >> 3, scol = (lane & 7) * 8;   // staging lane map

    f32x4 acc[4][4] = {};

    for (int k0 = 0; k0 < K; k0 += 64) {
        #pragma unroll
        for (int i = 0; i < 4; ++i) {
            int chunk = w * 4 + i;                 // 0..15, rows chunk*8..+8
            int row = chunk * 8 + srow;
            gld_lds16(&A [(size_t)(bm + row) * K + k0 + scol], &As[chunk * 512]);
            gld_lds16(&Bt[(size_t)(bn + row) * K + k0 + scol], &Bs[chunk * 512]);
        }
        __syncthreads();   // compiler drains vmcnt before barrier
        #pragma unroll
        for (int kk = 0; kk < 2; ++kk) {
            bf16x8 a[4], b[4];
            #pragma unroll
            for (int m = 0; m < 4; ++m)
                a[m] = *reinterpret_cast<const bf16x8*>(
                    &As[(wr * 64 + m * 16 + l15) * 64 + kk * 32 + lg * 8]);
            #pragma unroll
            for (int n = 0; n < 4; ++n)
                b[n] = *reinterpret_cast<const bf16x8*>(
                    &Bs[(wc * 64 + n * 16 + l15) * 64 + kk * 32 + lg * 8]);
            #pragma unroll
            for (int m = 0; m < 4; ++m)
                #pragma unroll
                for (int n = 0; n < 4; ++n)
                    acc[m][n] = __builtin_amdgcn_mfma_f32_16x16x32_bf16(
                        a[m], b[n], acc[m][n], 0, 0, 0);
        }
        __syncthreads();
    }

    const int orow0 = bm + wr * 64, ocol0 = bn + wc * 64;
    #pragma unroll
    for (int m = 0; m < 4; ++m)
        #pragma unroll
        for (int n = 0; n < 4; ++n)
            #pragma unroll
            for (int r = 0; r < 4; ++r) {
                int row = orow0 + m * 16 + lg * 4 + r;
                int col = ocol0 + n * 16 + l15;
                float v = acc[m][n][r];
                if (OUT_BF16)
                    ((u16*)Cv)[(size_t)row * N + col] = f2bf(v);
                else
                    ((float*)Cv)[(size_t)row * N + col] = v;
            }
}

// ------------------------------------------------------------------
// RMSNorm (full DIM row) + RoPE, in place on bf16 buffer, row stride 3072.
// ------------------------------------------------------------------
template<int DIM, int COLOFF>
__global__ __launch_bounds__(256) void rmsnorm_rope_bf(
    u16* __restrict__ x, const float* __restrict__ w,
    const float* __restrict__ cosb, const float* __restrict__ sinb)
{
    __shared__ float row[DIM];
    __shared__ float red[4];
    const int t = blockIdx.x, tid = threadIdx.x;
    u16* base = x + (size_t)t * 3072 + COLOFF;

    float ss = 0.f;
    for (int i0 = tid * 8; i0 < DIM; i0 += 2048) {
        uint4 u = *reinterpret_cast<const uint4*>(&base[i0]);
        const u16* us = reinterpret_cast<const u16*>(&u);
        #pragma unroll
        for (int j = 0; j < 8; ++j) { float f = bf2f(us[j]); row[i0 + j] = f; ss += f * f; }
    }
    #pragma unroll
    for (int off = 1; off < 64; off <<= 1) ss += __shfl_xor(ss, off);
    if ((tid & 63) == 0) red[tid >> 6] = ss;
    __syncthreads();
    const float var  = (red[0] + red[1] + red[2] + red[3]) * (1.0f / DIM);
    const float rstd = rsqrtf(var + 1e-6f);

    for (int i0 = tid * 8; i0 < DIM; i0 += 2048) {
        u16 o[8];
        #pragma unroll
        for (int j = 0; j < 8; ++j) {
            int i = i0 + j, dh = i & 63, bb = i & ~63;
            int oi = (dh < 32) ? bb + dh + 32 : bb + dh - 32;
            float y     = row[i]  * rstd * w[i];
            float other = row[oi] * rstd * w[oi];
            if (dh < 32) other = -other;
            float c  = cosb[(size_t)t * 64 + dh];
            float sn = sinb[(size_t)t * 64 + dh];
            o[j] = f2bf(y * c + other * sn);
        }
        *reinterpret_cast<uint4*>(&base[i0]) = *reinterpret_cast<uint4*>(o);
    }
}

// ------------------------------------------------------------------
// V transpose: qkv_bf V-cols -> vT bf16 [(b*8+kvh)*64 + d][1024]
// ------------------------------------------------------------------
__global__ __launch_bounds__(256) void v_transpose(
    const u16* __restrict__ qkv, u16* __restrict__ vT)
{
    __shared__ u16 t[64][72];
    const int hd = blockIdx.x;          // b*8 + kvh
    const int s0 = blockIdx.y * 64;
    const int b = hd >> 3, kvh = hd & 7;
    const int tid = threadIdx.x;
    #pragma unroll
    for (int i = 0; i < 2; ++i) {
        int chunk = i * 256 + tid;      // 0..511
        int r = chunk >> 3, c8 = (chunk & 7) * 8;
        uint4 u = *reinterpret_cast<const uint4*>(
            &qkv[(size_t)(b * 1024 + s0 + r) * 3072 + 2560 + kvh * 64 + c8]);
        *reinterpret_cast<uint4*>(&t[r][c8]) = u;
    }
    __syncthreads();
    #pragma unroll
    for (int i = 0; i < 2; ++i) {
        int chunk = i * 256 + tid;
        int d = chunk >> 3, c8 = (chunk & 7) * 8;
        u16 o[8];
        #pragma unroll
        for (int j = 0; j < 8; ++j) o[j] = t[c8 + j][d];
        *reinterpret_cast<uint4*>(&vT[((size_t)(hd * 64 + d)) * 1024 + s0 + c8])
            = *reinterpret_cast<uint4*>(o);
    }
}

// ------------------------------------------------------------------
// MFMA flash attention. grid (B*NH, S/64). 4 waves: wave w owns q-rows
// qt*64 + w*16 .. +16. Key tiles of 64, K staged row-major, V staged
// transposed (Vs[d][key]); online softmax in verified C/D layout.
// ------------------------------------------------------------------
__global__ __launch_bounds__(256) void attn_mfma(
    const u16* __restrict__ qkv,  // [2048][3072] (Q cols 0.., K cols 2048..)
    const u16* __restrict__ vT,   // [16*64][1024]
    u16* __restrict__ ob)         // [2048][2048]
{
    __shared__ u16 Ks[64 * 64];
    __shared__ u16 Vs[64 * 64];
    __shared__ u16 Ps[4][16 * 64];
    const int head = blockIdx.x;   // b*32 + h
    const int qt   = blockIdx.y;
    const int b = head >> 5, h = head & 31;
    const int kvh = h >> 2;
    const int tid = threadIdx.x, w = tid >> 6, lane = tid & 63;
    const int l15 = lane & 15, lg = lane >> 4;

    // Q fragments (held in registers for the whole block)
    bf16x8 qf[2];
    const size_t qrow = (size_t)(b * 1024 + qt * 64 + w * 16 + l15);
    #pragma unroll
    for (int kk = 0; kk < 2; ++kk)
        qf[kk] = *reinterpret_cast<const bf16x8*>(
            &qkv[qrow * 3072 + h * 64 + kk * 32 + lg * 8]);

    float mrun[4], lrun[4];
    #pragma unroll
    for (int r = 0; r < 4; ++r) { mrun[r] = -1e30f; lrun[r] = 0.f; }
    f32x4 oacc[4] = {};

    const u16* kbase = qkv + 2048 + kvh * 64;
    const u16* vbase = vT + (size_t)((b * 8 + kvh) * 64) * 1024;

    for (int kt = 0; kt <= qt; ++kt) {
        __syncthreads();   // all waves done reading Ks/Vs of previous tile
        #pragma unroll
        for (int i = 0; i < 2; ++i) {
            int chunk = w * 2 + i;   // 0..7, 8 rows each
            gld_lds16(&kbase[(size_t)(b * 1024 + kt * 64 + chunk * 8 + (lane >> 3)) * 3072
                             + (lane & 7) * 8],
                      &Ks[chunk * 512]);
            gld_lds16(&vbase[(size_t)(chunk * 8 + (lane >> 3)) * 1024
                             + kt * 64 + (lane & 7) * 8],
                      &Vs[chunk * 512]);
        }
        __syncthreads();   // staging visible

        // QK^T
        f32x4 sacc[4] = {};
        #pragma unroll
        for (int kk = 0; kk < 2; ++kk)
            #pragma unroll
            for (int n = 0; n < 4; ++n) {
                bf16x8 kf = *reinterpret_cast<const bf16x8*>(
                    &Ks[(n * 16 + l15) * 64 + kk * 32 + lg * 8]);
                sacc[n] = __builtin_amdgcn_mfma_f32_16x16x32_bf16(
                    qf[kk], kf, sacc[n], 0, 0, 0);
            }

        // softmax (C/D layout: lane holds rows lg*4+r, key col l15 + 16n)
        const bool diag = (kt == qt);
        float p[4][4], alpha[4];
        #pragma unroll
        for (int r = 0; r < 4; ++r) {
            float mx = -1e30f;
            #pragma unroll
            for (int n = 0; n < 4; ++n) {
                float s = sacc[n][r] * 0.125f;
                if (diag && (n * 16 + l15 > w * 16 + lg * 4 + r)) s = -1e30f;
                p[n][r] = s;
                mx = fmaxf(mx, s);
            }
            mx = fmaxf(mx, __shfl_xor(mx, 1));
            mx = fmaxf(mx, __shfl_xor(mx, 2));
            mx = fmaxf(mx, __shfl_xor(mx, 4));
            mx = fmaxf(mx, __shfl_xor(mx, 8));
            float mnew = fmaxf(mrun[r], mx);
            alpha[r] = __expf(mrun[r] - mnew);
            mrun[r] = mnew;
            float ls = 0.f;
            #pragma unroll
            for (int n = 0; n < 4; ++n) {
                float e = __expf(p[n][r] - mnew);
                p[n][r] = e;
                ls += e;
            }
            ls += __shfl_xor(ls, 1); ls += __shfl_xor(ls, 2);
            ls += __shfl_xor(ls, 4); ls += __shfl_xor(ls, 8);
            lrun[r] = lrun[r] * alpha[r] + ls;
        }

        // P -> per-wave LDS (bf16), then rescale O
        #pragma unroll
        for (int n = 0; n < 4; ++n)
            #pragma unroll
            for (int r = 0; r < 4; ++r)
                Ps[w][(lg * 4 + r) * 64 + n * 16 + l15] = f2bf(p[n][r]);
        #pragma unroll
        for (int d = 0; d < 4; ++d)
            #pragma unroll
            for (int r = 0; r < 4; ++r)
                oacc[d][r] *= alpha[r];

        asm volatile("s_waitcnt lgkmcnt(0)" ::: "memory");  // Ps cross-lane visible

        // PV
        #pragma unroll
        for (int kk = 0; kk < 2; ++kk) {
            bf16x8 pf = *reinterpret_cast<const bf16x8*>(
                &Ps[w][l15 * 64 + kk * 32 + lg * 8]);
            #pragma unroll
            for (int d = 0; d < 4; ++d) {
                bf16x8 vf = *reinterpret_cast<const bf16x8*>(
                    &Vs[(d * 16 + l15) * 64 + kk * 32 + lg * 8]);
                oacc[d] = __builtin_amdgcn_mfma_f32_16x16x32_bf16(
                    pf, vf, oacc[d], 0, 0, 0);
            }
        }
    }

    #pragma unroll
    for (int r = 0; r < 4; ++r) {
        float inv = 1.f / lrun[r];
        #pragma unroll
        for (int d = 0; d < 4; ++d)
            ob[(size_t)(b * 1024 + qt * 64 + w * 16 + lg * 4 + r) * 2048
               + h * 64 + d * 16 + l15] = f2bf(oacc[d][r] * inv);
    }
}

// ------------------------------------------------------------------
extern "C" void kernel_launch(void* const* d_in, const int* in_sizes, int n_in,
                              void* d_out, int out_size, void* d_ws, size_t ws_size,
                              hipStream_t stream)
{
    const float* hidden = (const float*)d_in[0];
    const float* cosb   = (const float*)d_in[1];
    const float* sinb   = (const float*)d_in[2];
    // d_in[3] = attention_mask (pure causal; handled analytically)
    const float* wq     = (const float*)d_in[4];
    const float* wk     = (const float*)d_in[5];
    const float* wv     = (const float*)d_in[6];
    const float* wo     = (const float*)d_in[7];
    const float* qnw    = (const float*)d_in[8];
    const float* knw    = (const float*)d_in[9];
    float* out = (float*)d_out;

    char* ws = (char*)d_ws;
    u16* hidden_bf = (u16*)ws;                          // 8MB  [0,8M)  -> later woT
    u16* woT       = (u16*)ws;
    u16* wqkvT     = (u16*)(ws + ((size_t)8  << 20));   // 12MB [8,20)  -> later attn_bf
    u16* attn_bf   = (u16*)(ws + ((size_t)8  << 20));
    u16* qkv_bf    = (u16*)(ws + ((size_t)20 << 20));   // 12MB [20,32)
    u16* v_bfT     = (u16*)(ws + ((size_t)32 << 20));   // 2MB  [32,34)

    cvt_bf16<<<2048, 256, 0, stream>>>(hidden, hidden_bf, 2048 * 2048);
    pack_wqkvT<<<dim3(48, 32), 256, 0, stream>>>(wq, wk, wv, wqkvT);

    // fused QKV projection: [2048,2048] @ [2048,3072] -> bf16 [2048,3072]
    gemm_bt<true><<<dim3(24, 16), 256, 0, stream>>>(hidden_bf, wqkvT, qkv_bf,
                                                    2048, 3072, 2048);

    // wo transpose into the (now free) hidden_bf region
    transpose_cvt<<<dim3(32, 32), 256, 0, stream>>>(wo, woT, 2048, 2048);

    rmsnorm_rope_bf<2048, 0>   <<<T_, 256, 0, stream>>>(qkv_bf, qnw, cosb, sinb);
    rmsnorm_rope_bf<512,  2048><<<T_, 256, 0, stream>>>(qkv_bf, knw, cosb, sinb);
    v_transpose<<<dim3(16, 16), 256, 0, stream>>>(qkv_bf, v_bfT);

    // attention -> attn_bf (aliases wqkvT region, free after QKV GEMM)
    attn_mfma<<<dim3(B_ * NH_, S_ / 64), 256, 0, stream>>>(qkv_bf, v_bfT, attn_bf);

    // output projection: [2048,2048] @ [2048,2048]^T(of woT) -> fp32 out
    gemm_bt<false><<<dim3(16, 16), 256, 0, stream>>>(attn_bf, woT, out,
                                                     2048, 2048, 2048);
}

// Round 3
// 148.756 us; speedup vs baseline: 7.1197x; 1.2629x over previous
//
#include <hip/hip_runtime.h>

#define B_    2
#define S_    1024
#define NH_   32
#define NKV_  8
#define T_    (B_*S_)

typedef unsigned short u16;
typedef __attribute__((ext_vector_type(8))) short bf16x8;
typedef __attribute__((ext_vector_type(4))) float f32x4;

__device__ __forceinline__ float bf2f(u16 u) {
    union { float f; unsigned int i; } c; c.i = ((unsigned int)u) << 16; return c.f;
}
__device__ __forceinline__ u16 f2bf(float f) {
    union { float f; unsigned int u; } c; c.f = f;
    return (u16)((c.u + 0x7FFFu + ((c.u >> 16) & 1u)) >> 16);
}

// async global->LDS, 16B per lane; LDS dest = wave-uniform base + lane*16 (linear)
__device__ __forceinline__ void gld_lds16(const void* g, void* s) {
    __builtin_amdgcn_global_load_lds(
        (const __attribute__((address_space(1))) void*)g,
        (__attribute__((address_space(3))) void*)s,
        16, 0, 0);
}

// ------------------------------------------------------------------
// preproc1: blocks [0,2048) convert hidden f32->bf16;
//           blocks [2048,3584) pack wq|wk|wv transposed -> bf16 [3072][2048]
// ------------------------------------------------------------------
__global__ __launch_bounds__(256) void preproc1(
    const float* __restrict__ hidden, const float* __restrict__ wq,
    const float* __restrict__ wk, const float* __restrict__ wv,
    u16* __restrict__ hidden_bf, u16* __restrict__ wqkvT)
{
    __shared__ float t[64][65];
    const int bid = blockIdx.x, tid = threadIdx.x;
    if (bid < 2048) {
        int i = (bid * 256 + tid) * 8;
        float4 v0 = *reinterpret_cast<const float4*>(&hidden[i]);
        float4 v1 = *reinterpret_cast<const float4*>(&hidden[i + 4]);
        u16 o[8] = { f2bf(v0.x), f2bf(v0.y), f2bf(v0.z), f2bf(v0.w),
                     f2bf(v1.x), f2bf(v1.y), f2bf(v1.z), f2bf(v1.w) };
        *reinterpret_cast<uint4*>(&hidden_bf[i]) = *reinterpret_cast<uint4*>(o);
        return;
    }
    const int tt = bid - 2048;
    const int n0 = (tt % 48) * 64, k0 = (tt / 48) * 64;
    const float* src; int scol, sN;
    if (n0 < 2048)      { src = wq; scol = n0;        sN = 2048; }
    else if (n0 < 2560) { src = wk; scol = n0 - 2048; sN = 512;  }
    else                { src = wv; scol = n0 - 2560; sN = 512;  }
    #pragma unroll
    for (int i = 0; i < 16; ++i) {
        int e = i * 256 + tid, r = e >> 6, c = e & 63;
        t[r][c] = src[(size_t)(k0 + r) * sN + scol + c];
    }
    __syncthreads();
    #pragma unroll
    for (int i = 0; i < 16; ++i) {
        int e = i * 256 + tid, rr = e >> 6, cc = e & 63;
        wqkvT[(size_t)(n0 + rr) * 2048 + k0 + cc] = f2bf(t[cc][rr]);
    }
}

// ------------------------------------------------------------------
// preproc2: blocks [0,1024) transpose wo f32[2048][2048] -> woT bf16;
//           blocks [1024,1280) V transpose -> vT [(b*8+kvh)*64+d][1024]
// ------------------------------------------------------------------
__global__ __launch_bounds__(256) void preproc2(
    const float* __restrict__ wo, u16* __restrict__ woT,
    const u16* __restrict__ qkv, u16* __restrict__ vT)
{
    __shared__ float t[64][65];
    __shared__ u16 tu[64][72];
    const int bid = blockIdx.x, tid = threadIdx.x;
    if (bid < 1024) {
        const int n0 = (bid % 32) * 64, k0 = (bid / 32) * 64;
        #pragma unroll
        for (int i = 0; i < 16; ++i) {
            int e = i * 256 + tid, r = e >> 6, c = e & 63;
            t[r][c] = wo[(size_t)(k0 + r) * 2048 + n0 + c];
        }
        __syncthreads();
        #pragma unroll
        for (int i = 0; i < 16; ++i) {
            int e = i * 256 + tid, rr = e >> 6, cc = e & 63;
            woT[(size_t)(n0 + rr) * 2048 + k0 + cc] = f2bf(t[cc][rr]);
        }
        return;
    }
    const int bid2 = bid - 1024;
    const int hd = bid2 % 16;              // b*8 + kvh
    const int s0 = (bid2 / 16) * 64;
    const int b = hd >> 3, kvh = hd & 7;
    #pragma unroll
    for (int i = 0; i < 2; ++i) {
        int chunk = i * 256 + tid;
        int r = chunk >> 3, c8 = (chunk & 7) * 8;
        uint4 u = *reinterpret_cast<const uint4*>(
            &qkv[(size_t)(b * 1024 + s0 + r) * 3072 + 2560 + kvh * 64 + c8]);
        *reinterpret_cast<uint4*>(&tu[r][c8]) = u;
    }
    __syncthreads();
    #pragma unroll
    for (int i = 0; i < 2; ++i) {
        int chunk = i * 256 + tid;
        int d = chunk >> 3, c8 = (chunk & 7) * 8;
        u16 o[8];
        #pragma unroll
        for (int j = 0; j < 8; ++j) o[j] = tu[c8 + j][d];
        *reinterpret_cast<uint4*>(&vT[((size_t)(hd * 64 + d)) * 1024 + s0 + c8])
            = *reinterpret_cast<uint4*>(o);
    }
}

// ------------------------------------------------------------------
// bf16 MFMA GEMM, B^T input. C[M,N] = A[M,K] @ Bt[N,K]^T
// 128x128 tile, BK=64, 4 waves (2x2), T2 XOR-swizzled LDS,
// double-buffered staging with counted vmcnt (T3/T4).
// ------------------------------------------------------------------
template<bool OUT_BF16>
__global__ __launch_bounds__(256) void gemm_bt(
    const u16* __restrict__ A, const u16* __restrict__ Bt,
    void* __restrict__ Cv, int M, int N, int K)
{
    __shared__ u16 As[2][128 * 64];
    __shared__ u16 Bs[2][128 * 64];
    const int bm = blockIdx.y * 128, bn = blockIdx.x * 128;
    const int tid = threadIdx.x;
    const int w = tid >> 6, lane = tid & 63;
    const int wr = w >> 1, wc = w & 1;
    const int l15 = lane & 15, lg = lane >> 4;
    const int srow = lane >> 3;                       // 0..7
    const int scolsw = (lane & 7) ^ srow;             // swizzled source 16B-chunk

    f32x4 acc[4][4] = {};
    const int nk = K >> 6;

#define GSTAGE(ks, bb) do {                                                    \
    const int kofs = (ks) * 64;                                                \
    _Pragma("unroll")                                                          \
    for (int i_ = 0; i_ < 4; ++i_) {                                           \
        int chunk_ = w * 4 + i_;                                               \
        int row_ = chunk_ * 8 + srow;                                          \
        gld_lds16(&A [(size_t)(bm + row_) * K + kofs + scolsw * 8],            \
                  &As[bb][chunk_ * 512]);                                      \
        gld_lds16(&Bt[(size_t)(bn + row_) * K + kofs + scolsw * 8],            \
                  &Bs[bb][chunk_ * 512]);                                      \
    } } while (0)

    GSTAGE(0, 0);
    for (int ks = 0; ks < nk; ++ks) {
        const int cur = ks & 1;
        if (ks + 1 < nk) {
            GSTAGE(ks + 1, cur ^ 1);
            asm volatile("s_waitcnt vmcnt(8)" ::: "memory");
        } else {
            asm volatile("s_waitcnt vmcnt(0)" ::: "memory");
        }
        __builtin_amdgcn_sched_barrier(0);
        __builtin_amdgcn_s_barrier();
        __builtin_amdgcn_sched_barrier(0);

        #pragma unroll
        for (int kk = 0; kk < 2; ++kk) {
            const int phys = ((kk * 4 + lg) ^ (l15 & 7)) * 8;
            bf16x8 a[4], b[4];
            #pragma unroll
            for (int m = 0; m < 4; ++m)
                a[m] = *reinterpret_cast<const bf16x8*>(
                    &As[cur][(wr * 64 + m * 16 + l15) * 64 + phys]);
            #pragma unroll
            for (int n = 0; n < 4; ++n)
                b[n] = *reinterpret_cast<const bf16x8*>(
                    &Bs[cur][(wc * 64 + n * 16 + l15) * 64 + phys]);
            #pragma unroll
            for (int m = 0; m < 4; ++m)
                #pragma unroll
                for (int n = 0; n < 4; ++n)
                    acc[m][n] = __builtin_amdgcn_mfma_f32_16x16x32_bf16(
                        a[m], b[n], acc[m][n], 0, 0, 0);
        }
        __builtin_amdgcn_sched_barrier(0);
        __builtin_amdgcn_s_barrier();   // protect buffer reuse next iter
    }
#undef GSTAGE

    const int orow0 = bm + wr * 64, ocol0 = bn + wc * 64;
    #pragma unroll
    for (int m = 0; m < 4; ++m)
        #pragma unroll
        for (int n = 0; n < 4; ++n)
            #pragma unroll
            for (int r = 0; r < 4; ++r) {
                int row = orow0 + m * 16 + lg * 4 + r;
                int col = ocol0 + n * 16 + l15;
                float v = acc[m][n][r];
                if (OUT_BF16)
                    ((u16*)Cv)[(size_t)row * N + col] = f2bf(v);
                else
                    ((float*)Cv)[(size_t)row * N + col] = v;
            }
}

// ------------------------------------------------------------------
// Merged RMSNorm+RoPE for Q (2048 ch) then K (512 ch), in place.
// ------------------------------------------------------------------
template<int DIM>
__device__ __forceinline__ void rms_rope_row(
    u16* base, const float* __restrict__ w,
    const float* __restrict__ cs, const float* __restrict__ sn,
    float* row, float* red, int tid)
{
    float ss = 0.f;
    for (int i0 = tid * 8; i0 < DIM; i0 += 2048) {
        uint4 u = *reinterpret_cast<const uint4*>(&base[i0]);
        const u16* us = reinterpret_cast<const u16*>(&u);
        #pragma unroll
        for (int j = 0; j < 8; ++j) { float f = bf2f(us[j]); row[i0 + j] = f; ss += f * f; }
    }
    #pragma unroll
    for (int off = 1; off < 64; off <<= 1) ss += __shfl_xor(ss, off);
    if ((tid & 63) == 0) red[tid >> 6] = ss;
    __syncthreads();
    const float rstd = rsqrtf((red[0] + red[1] + red[2] + red[3]) * (1.0f / DIM) + 1e-6f);

    for (int i0 = tid * 8; i0 < DIM; i0 += 2048) {
        u16 o[8];
        #pragma unroll
        for (int j = 0; j < 8; ++j) {
            int i = i0 + j, dh = i & 63, bb = i & ~63;
            int oi = (dh < 32) ? bb + dh + 32 : bb + dh - 32;
            float y     = row[i]  * rstd * w[i];
            float other = row[oi] * rstd * w[oi];
            if (dh < 32) other = -other;
            o[j] = f2bf(y * cs[dh] + other * sn[dh]);
        }
        *reinterpret_cast<uint4*>(&base[i0]) = *reinterpret_cast<uint4*>(o);
    }
}

__global__ __launch_bounds__(256) void rmsnorm_rope_qk(
    u16* __restrict__ x, const float* __restrict__ qnw, const float* __restrict__ knw,
    const float* __restrict__ cosb, const float* __restrict__ sinb)
{
    __shared__ float row[2048];
    __shared__ float red[4];
    const int t = blockIdx.x, tid = threadIdx.x;
    const float* cs = cosb + (size_t)t * 64;
    const float* sn = sinb + (size_t)t * 64;
    rms_rope_row<2048>(x + (size_t)t * 3072,        qnw, cs, sn, row, red, tid);
    __syncthreads();
    rms_rope_row<512 >(x + (size_t)t * 3072 + 2048, knw, cs, sn, row, red, tid);
}

// ------------------------------------------------------------------
// MFMA flash attention v2: swapped QK^T (in-reg softmax), XOR-swizzled
// LDS, double-buffered K/V staging with counted vmcnt + raw barriers.
// grid (B*NH, S/64), 4 waves; wave w owns q-rows qt*64+w*16..+16.
// ------------------------------------------------------------------
__global__ __launch_bounds__(256) void attn_mfma(
    const u16* __restrict__ qkv,  // [2048][3072]
    const u16* __restrict__ vT,   // [16*64][1024]
    u16* __restrict__ ob)         // [2048][2048]
{
    __shared__ u16 Ks[2][64 * 64];
    __shared__ u16 Vs[2][64 * 64];
    __shared__ u16 Ps[4][16 * 64];
    const int head = blockIdx.x;   // b*32 + h
    const int qt   = blockIdx.y;
    const int b = head >> 5, h = head & 31;
    const int kvh = h >> 2;
    const int tid = threadIdx.x, w = tid >> 6, lane = tid & 63;
    const int l15 = lane & 15, lg = lane >> 4;
    const int srow = lane >> 3;
    const int scolsw = (lane & 7) ^ srow;

    // Q fragments in registers (q-row = l15 of wave's 16)
    bf16x8 qf[2];
    const size_t qrow = (size_t)(b * 1024 + qt * 64 + w * 16 + l15);
    #pragma unroll
    for (int kk = 0; kk < 2; ++kk)
        qf[kk] = *reinterpret_cast<const bf16x8*>(
            &qkv[qrow * 3072 + h * 64 + kk * 32 + lg * 8]);
    asm volatile("s_waitcnt vmcnt(0)" ::: "memory");  // clean vmcnt for pipeline

    float mr = -1e30f, lr = 0.f;     // per-lane state for q = w*16 + l15
    f32x4 oacc[4] = {};

    const u16* kbase = qkv + 2048 + kvh * 64;
    const u16* vbase = vT + (size_t)((b * 8 + kvh) * 64) * 1024;
    const int qg = qt * 64 + w * 16 + l15;

#define ASTAGE(kt, bb) do {                                                    \
    _Pragma("unroll")                                                          \
    for (int i_ = 0; i_ < 2; ++i_) {                                           \
        int chunk_ = w * 2 + i_;                                               \
        int row_ = chunk_ * 8 + srow;                                          \
        gld_lds16(&kbase[(size_t)(b * 1024 + (kt) * 64 + row_) * 3072          \
                         + scolsw * 8], &Ks[bb][chunk_ * 512]);                \
        gld_lds16(&vbase[(size_t)row_ * 1024 + (kt) * 64 + scolsw * 8],        \
                  &Vs[bb][chunk_ * 512]);                                      \
    } } while (0)

    ASTAGE(0, 0);
    for (int kt = 0; kt <= qt; ++kt) {
        const int cur = kt & 1;
        if (kt < qt) {
            ASTAGE(kt + 1, cur ^ 1);
            asm volatile("s_waitcnt vmcnt(4)" ::: "memory");
        } else {
            asm volatile("s_waitcnt vmcnt(0)" ::: "memory");
        }
        __builtin_amdgcn_sched_barrier(0);
        __builtin_amdgcn_s_barrier();
        __builtin_amdgcn_sched_barrier(0);

        // swapped QK^T: D[key][q], lane holds q=l15, keys m*16+lg*4+r
        f32x4 sacc[4] = {};
        #pragma unroll
        for (int kk = 0; kk < 2; ++kk) {
            const int phys = ((kk * 4 + lg) ^ (l15 & 7)) * 8;
            #pragma unroll
            for (int m = 0; m < 4; ++m) {
                bf16x8 kf = *reinterpret_cast<const bf16x8*>(
                    &Ks[cur][(m * 16 + l15) * 64 + phys]);
                sacc[m] = __builtin_amdgcn_mfma_f32_16x16x32_bf16(
                    kf, qf[kk], sacc[m], 0, 0, 0);
            }
        }

        // in-register softmax (base-2 domain), 4 shuffles total
        float s2[4][4];
        float mx = -1e30f;
        #pragma unroll
        for (int m = 0; m < 4; ++m)
            #pragma unroll
            for (int r = 0; r < 4; ++r) {
                float v = sacc[m][r] * 0.18033688f;   // 0.125 * log2(e)
                if (kt * 64 + m * 16 + lg * 4 + r > qg) v = -1e30f;
                s2[m][r] = v;
                mx = fmaxf(mx, v);
            }
        mx = fmaxf(mx, __shfl_xor(mx, 16));
        mx = fmaxf(mx, __shfl_xor(mx, 32));
        const float mnew = fmaxf(mr, mx);
        const float alpha = exp2f(mr - mnew);
        mr = mnew;
        float ls = 0.f;
        #pragma unroll
        for (int m = 0; m < 4; ++m)
            #pragma unroll
            for (int r = 0; r < 4; ++r) {
                float e = (s2[m][r] <= -1e29f) ? 0.f : exp2f(s2[m][r] - mnew);
                s2[m][r] = e;
                ls += e;
            }
        ls += __shfl_xor(ls, 16); ls += __shfl_xor(ls, 32);
        lr = lr * alpha + ls;

        // P -> Ps[w] as [q=l15][key], swizzled; 4x ds_write_b64
        #pragma unroll
        for (int m = 0; m < 4; ++m) {
            u16 pk[4];
            #pragma unroll
            for (int r = 0; r < 4; ++r) pk[r] = f2bf(s2[m][r]);
            const int keyc = m * 16 + lg * 4;
            const int phys = (keyc >> 3) ^ (l15 & 7);
            *reinterpret_cast<uint2*>(&Ps[w][l15 * 64 + phys * 8 + (keyc & 7)])
                = *reinterpret_cast<const uint2*>(pk);
        }

        // rescale O: alpha for q = lg*4 + r (broadcast from lane lg*16+lg*4+r)
        float alq[4];
        #pragma unroll
        for (int r = 0; r < 4; ++r)
            alq[r] = __shfl(alpha, (lane & 48) + ((lane >> 4) & 3) * 4 + r);
        #pragma unroll
        for (int d = 0; d < 4; ++d)
            #pragma unroll
            for (int r = 0; r < 4; ++r)
                oacc[d][r] *= alq[r];

        asm volatile("s_waitcnt lgkmcnt(0)" ::: "memory");  // Ps writes done
        __builtin_amdgcn_sched_barrier(0);

        // PV: O[q][d] += P[q][key] * V[key][d]
        #pragma unroll
        for (int kk = 0; kk < 2; ++kk) {
            const int phys = ((kk * 4 + lg) ^ (l15 & 7)) * 8;
            bf16x8 pf = *reinterpret_cast<const bf16x8*>(
                &Ps[w][l15 * 64 + phys]);
            #pragma unroll
            for (int d = 0; d < 4; ++d) {
                bf16x8 vf = *reinterpret_cast<const bf16x8*>(
                    &Vs[cur][(d * 16 + l15) * 64 + phys]);
                oacc[d] = __builtin_amdgcn_mfma_f32_16x16x32_bf16(
                    pf, vf, oacc[d], 0, 0, 0);
            }
        }
        __builtin_amdgcn_sched_barrier(0);
        __builtin_amdgcn_s_barrier();   // all reads of cur done before reuse
    }
#undef ASTAGE

    // epilogue: lane holds O[q = w*16 + lg*4 + r][d = dblk*16 + l15]
    float linv[4];
    #pragma unroll
    for (int r = 0; r < 4; ++r) {
        float lv = __shfl(lr, (lane & 48) + ((lane >> 4) & 3) * 4 + r);
        linv[r] = 1.f / lv;
    }
    #pragma unroll
    for (int d = 0; d < 4; ++d)
        #pragma unroll
        for (int r = 0; r < 4; ++r)
            ob[(size_t)(b * 1024 + qt * 64 + w * 16 + lg * 4 + r) * 2048
               + h * 64 + d * 16 + l15] = f2bf(oacc[d][r] * linv[r]);
}

// ------------------------------------------------------------------
extern "C" void kernel_launch(void* const* d_in, const int* in_sizes, int n_in,
                              void* d_out, int out_size, void* d_ws, size_t ws_size,
                              hipStream_t stream)
{
    const float* hidden = (const float*)d_in[0];
    const float* cosb   = (const float*)d_in[1];
    const float* sinb   = (const float*)d_in[2];
    // d_in[3] = attention_mask (pure causal; handled analytically)
    const float* wq     = (const float*)d_in[4];
    const float* wk     = (const float*)d_in[5];
    const float* wv     = (const float*)d_in[6];
    const float* wo     = (const float*)d_in[7];
    const float* qnw    = (const float*)d_in[8];
    const float* knw    = (const float*)d_in[9];
    float* out = (float*)d_out;

    char* ws = (char*)d_ws;
    u16* hidden_bf = (u16*)ws;                          // [0,8M)  -> later woT
    u16* woT       = (u16*)ws;
    u16* wqkvT     = (u16*)(ws + ((size_t)8  << 20));   // [8,20M) -> later attn_bf
    u16* attn_bf   = (u16*)(ws + ((size_t)8  << 20));
    u16* qkv_bf    = (u16*)(ws + ((size_t)20 << 20));   // [20,32M)
    u16* v_bfT     = (u16*)(ws + ((size_t)32 << 20));   // [32,34M)

    // hidden -> bf16, wq|wk|wv -> transposed bf16
    preproc1<<<3584, 256, 0, stream>>>(hidden, wq, wk, wv, hidden_bf, wqkvT);

    // fused QKV projection: [2048,2048] @ [2048,3072] -> bf16 [2048,3072]
    gemm_bt<true><<<dim3(24, 16), 256, 0, stream>>>(hidden_bf, wqkvT, qkv_bf,
                                                    2048, 3072, 2048);

    // RMSNorm + RoPE for Q and K (in place)
    rmsnorm_rope_qk<<<T_, 256, 0, stream>>>(qkv_bf, qnw, knw, cosb, sinb);

    // wo transpose (into freed hidden_bf region) + V transpose
    preproc2<<<1280, 256, 0, stream>>>(wo, woT, qkv_bf, v_bfT);

    // attention -> attn_bf (aliases wqkvT region, free after QKV GEMM)
    attn_mfma<<<dim3(B_ * NH_, S_ / 64), 256, 0, stream>>>(qkv_bf, v_bfT, attn_bf);

    // output projection: [2048,2048] @ woT^T -> fp32 out
    gemm_bt<false><<<dim3(16, 16), 256, 0, stream>>>(attn_bf, woT, out,
                                                     2048, 2048, 2048);
}